// Round 9
// baseline (322.912 us; speedup 1.0000x reference)
//
#include <hip/hip_runtime.h>

typedef unsigned short u16;
typedef __attribute__((ext_vector_type(4))) float f32x4;
typedef __attribute__((ext_vector_type(8))) __bf16 bf16x8;

// ---------- helpers ----------
__device__ __forceinline__ u16 f2bf(float f) {
    unsigned int x = __float_as_uint(f);
    x += 0x7fffu + ((x >> 16) & 1u);          // RNE
    return (u16)(x >> 16);
}
__device__ __forceinline__ float bf2f(u16 u) {
    return __uint_as_float(((unsigned int)u) << 16);
}
__device__ __forceinline__ void async16(const void* g, void* l) {
    __builtin_amdgcn_global_load_lds(
        (const __attribute__((address_space(1))) void*)g,
        (__attribute__((address_space(3))) void*)l,
        16, 0, 0);
}
__device__ __forceinline__ void barrier_fence() {
    asm volatile("" ::: "memory");
    __builtin_amdgcn_s_barrier();
    asm volatile("" ::: "memory");
}
__device__ __forceinline__ unsigned cvtpk(float lo, float hi) {
    unsigned d;
    asm("v_cvt_pk_bf16_f32 %0, %1, %2" : "=v"(d) : "v"(lo), "v"(hi));
    return d;
}

// ---------- GEMM1 + fused RoPE, fp32 inputs: qkv = x * [Wq|Wkv]^T ----------
// 512 threads / 8 waves, 128x128 tile, BK=32, 2 LDS bf16 buffers (32 KB).
// A,B consumed in fp32 directly (no cvt pass): each wave reg-stages its
// quarter (4x dwordx4 -> cvt_pk -> 2 swizzled ds_write_b128); loads for
// tile t+1 in flight across the whole of iter t. Redundant fp32 re-reads
// are L3-resident. RoPE fused in epilogue (b-frag cols wn*16 and +64 pair
// in-lane); v-cols scattered to vbuf. Blocks raw>=768 convert wo instead
// (read only by the final GEMM, two dispatches later).
__global__ __launch_bounds__(512, 4)
void gemm_qkv_f32(const float* __restrict__ A,
                  const float* __restrict__ B0,
                  const float* __restrict__ B1,
                  const float* __restrict__ wo,
                  u16* __restrict__ wob,
                  u16* __restrict__ C,
                  u16* __restrict__ vbuf,
                  int M, int K)
{
    const int raw = blockIdx.x;
    const int tid = threadIdx.x;

    if (raw >= 768) {                    // ---- wo fp32->bf16 side task ----
        int idx = (raw - 768) * 512 + tid;
        #pragma unroll 4
        for (int p = 0; p < 32; ++p) {
            const int i = (idx + p * 32768) * 4;
            const float4 v = *(const float4*)(wo + i);
            ushort4 o;
            o.x = f2bf(v.x); o.y = f2bf(v.y); o.z = f2bf(v.z); o.w = f2bf(v.w);
            *(ushort4*)(wob + i) = o;
        }
        return;
    }

    __shared__ __align__(16) u16 As[2][4096];     // [buf][128 rows x 32]
    __shared__ __align__(16) u16 Bs[2][4096];

    const int w    = tid >> 6;           // 0..7
    const int lane = tid & 63;
    const int fl   = lane & 15;
    const int q4   = lane >> 4;
    const int wm   = w >> 2;             // 0..1 : 64-row slice
    const int wn   = w & 3;              // 0..3 : 16-col pair group

    int id = (raw & 7) * 96 + (raw >> 3);         // bijective XCD swizzle /768
    const int m0 = (id / 24) * 128;
    const int n0 = (id % 24) * 128;

    const float* Bp = B0;
    int nb = n0;
    if (n0 >= 2048) { Bp = B1; nb = n0 - 2048; }

    // ---- staging role: waves 0-3 stage A, 4-7 stage B ----
    const int wq   = w & 3;
    const int srow = wq * 32 + (lane >> 1);       // 0..127
    const int ch   = lane & 1;                    // 16-float column half
    const bool isA = (w < 4);
    const float* sp = isA ? (A + (size_t)(m0 + srow) * K + ch * 16)
                          : (Bp + (size_t)(nb + srow) * K + ch * 16);
    u16* sl = isA ? &As[0][0] : &Bs[0][0];
    // write slots: granules g0=2ch, g0+1 at slot g ^ f, f=(srow>>1)&3
    const int f_   = (lane >> 2) & 3;
    const int s0   = (2 * ch) ^ f_;
    const int s1   = (2 * ch + 1) ^ f_;
    const int wbase = srow * 32;

    // ---- fragment read addressing ----
    const int cSlot = (q4 ^ ((fl >> 1) & 3)) * 8;
    const int aBase = (wm * 64 + fl) * 32 + cSlot;
    const int bBase0 = (wn * 16 + fl) * 32 + cSlot;          // cols wn*16+..
    const int bBase1 = (64 + wn * 16 + fl) * 32 + cSlot;     // cols +64

    f32x4 acc[4][2];
    #pragma unroll
    for (int i = 0; i < 4; ++i) {
        acc[i][0] = f32x4{0.f, 0.f, 0.f, 0.f};
        acc[i][1] = f32x4{0.f, 0.f, 0.f, 0.f};
    }

    const int NT = K >> 5;               // 64 K-steps
    float4 L[4];

    auto issueLoads = [&](int t) {
        const float* p = sp + (size_t)t * 32;
        L[0] = *(const float4*)(p);
        L[1] = *(const float4*)(p + 4);
        L[2] = *(const float4*)(p + 8);
        L[3] = *(const float4*)(p + 12);
    };

    // prologue: tile0 staged, tile1 loads in flight
    issueLoads(0);
    {
        unsigned g[8];
        g[0] = cvtpk(L[0].x, L[0].y); g[1] = cvtpk(L[0].z, L[0].w);
        g[2] = cvtpk(L[1].x, L[1].y); g[3] = cvtpk(L[1].z, L[1].w);
        g[4] = cvtpk(L[2].x, L[2].y); g[5] = cvtpk(L[2].z, L[2].w);
        g[6] = cvtpk(L[3].x, L[3].y); g[7] = cvtpk(L[3].z, L[3].w);
        unsigned* d0 = (unsigned*)(sl + wbase + s0 * 8);
        unsigned* d1 = (unsigned*)(sl + wbase + s1 * 8);
        d0[0] = g[0]; d0[1] = g[1]; d0[2] = g[2]; d0[3] = g[3];
        d1[0] = g[4]; d1[1] = g[5]; d1[2] = g[6]; d1[3] = g[7];
    }
    issueLoads(1);

    for (int t = 0; t < NT; ++t) {
        const int bf = t & 1;
        asm volatile("s_waitcnt lgkmcnt(0)" ::: "memory");
        barrier_fence();

        bf16x8 a[4], b[2];
        #pragma unroll
        for (int mt = 0; mt < 4; ++mt)
            a[mt] = *(const bf16x8*)&As[bf][aBase + mt * 512];
        b[0] = *(const bf16x8*)&Bs[bf][bBase0];
        b[1] = *(const bf16x8*)&Bs[bf][bBase1];

        #pragma unroll
        for (int mt = 0; mt < 4; ++mt) {
            acc[mt][0] = __builtin_amdgcn_mfma_f32_16x16x32_bf16(
                a[mt], b[0], acc[mt][0], 0, 0, 0);
            acc[mt][1] = __builtin_amdgcn_mfma_f32_16x16x32_bf16(
                a[mt], b[1], acc[mt][1], 0, 0, 0);
        }

        if (t + 1 < NT) {
            asm volatile("s_waitcnt vmcnt(0)" ::: "memory");
            unsigned g[8];
            g[0] = cvtpk(L[0].x, L[0].y); g[1] = cvtpk(L[0].z, L[0].w);
            g[2] = cvtpk(L[1].x, L[1].y); g[3] = cvtpk(L[1].z, L[1].w);
            g[4] = cvtpk(L[2].x, L[2].y); g[5] = cvtpk(L[2].z, L[2].w);
            g[6] = cvtpk(L[3].x, L[3].y); g[7] = cvtpk(L[3].z, L[3].w);
            u16* base = sl + ((t + 1) & 1) * 4096 + wbase;
            unsigned* d0 = (unsigned*)(base + s0 * 8);
            unsigned* d1 = (unsigned*)(base + s1 * 8);
            d0[0] = g[0]; d0[1] = g[1]; d0[2] = g[2]; d0[3] = g[3];
            d1[0] = g[4]; d1[1] = g[5]; d1[2] = g[6]; d1[3] = g[7];
            if (t + 2 < NT) issueLoads(t + 2);
        }
    }

    // ---- epilogue: fused RoPE (q/k) or vbuf scatter (v) ----
    if (n0 < 2560) {
        const float sc = (n0 < 2048) ? 0.08838834764831845f : 1.0f;
        const int i0 = wn * 16 + fl;                        // rope idx 0..63
        const float inv = exp2f(-(float)i0 * 0.2076205f);   // log2(1e4)/64
        #pragma unroll
        for (int mt = 0; mt < 4; ++mt) {
            #pragma unroll
            for (int r = 0; r < 4; ++r) {
                const int row = m0 + wm * 64 + mt * 16 + q4 * 4 + r;
                const float pos = (float)(row & 2047);
                float s, c;
                __sincosf(pos * inv, &s, &c);
                const float x1 = acc[mt][0][r];
                const float x2 = acc[mt][1][r];
                C[(size_t)row * 3072 + n0 + i0]      = f2bf((x1 * c - x2 * s) * sc);
                C[(size_t)row * 3072 + n0 + 64 + i0] = f2bf((x2 * c + x1 * s) * sc);
            }
        }
    } else {
        #pragma unroll
        for (int mt = 0; mt < 4; ++mt)
            #pragma unroll
            for (int j = 0; j < 2; ++j) {
                const int colb = n0 + j * 64 + wn * 16 + fl;
                const int fc = colb - 2560;
                #pragma unroll
                for (int r = 0; r < 4; ++r) {
                    const int row = m0 + wm * 64 + mt * 16 + q4 * 4 + r;
                    const int tt = row & 2047;
                    const int bb2 = row >> 11;
                    vbuf[((size_t)((bb2 << 2) + (fc >> 7)) * 128 + (fc & 127)) * 2048 + tt] =
                        f2bf(acc[mt][j][r]);
                }
            }
    }
}

// ---------- GEMM2: Cf = A[M,K] * B[N,K]^T, 128x128 (round-4, frozen) -------
__global__ __launch_bounds__(256, 3)
void gemm128r(const u16* __restrict__ A,
              const u16* __restrict__ B0,
              float* __restrict__ Cf,
              int M, int N, int K)
{
    constexpr int ASZ = 128 * 32;
    __shared__ __align__(16) u16 As[3 * ASZ];
    __shared__ __align__(16) u16 Bs[3 * ASZ];

    const int tid  = threadIdx.x;
    const int w    = tid >> 6;
    const int lane = tid & 63;
    const int fl   = lane & 15;
    const int q4   = lane >> 4;
    const int wm   = w >> 1;
    const int wn   = w & 1;

    const int gx  = gridDim.x;
    const int nwg = gx * gridDim.y;
    int id = blockIdx.y * gx + blockIdx.x;
    id = (id & 7) * (nwg >> 3) + (id >> 3);
    const int m0 = (id / gx) * 128;
    const int n0 = (id % gx) * 128;

    const int srow = w * 16 + (lane >> 2);
    const int sg   = (lane & 3) ^ ((lane >> 3) & 3);
    const u16* agp = A  + (size_t)(m0 + srow) * K + sg * 8;
    const u16* bgp = B0 + (size_t)(n0 + srow) * K + sg * 8;
    const int sLds = w * 512;

    const int cSlot = (q4 ^ ((fl >> 1) & 3)) * 8;

    f32x4 acc[4][4];
    #pragma unroll
    for (int i = 0; i < 4; ++i)
        #pragma unroll
        for (int j = 0; j < 4; ++j)
            acc[i][j] = f32x4{0.f, 0.f, 0.f, 0.f};

    const int NT = K >> 5;

    auto stage = [&](int t, int bf) {
        const size_t kof = (size_t)t * 32;
        async16(agp + kof,                   &As[bf * ASZ + sLds]);
        async16(agp + (size_t)64 * K + kof,  &As[bf * ASZ + 2048 + sLds]);
        async16(bgp + kof,                   &Bs[bf * ASZ + sLds]);
        async16(bgp + (size_t)64 * K + kof,  &Bs[bf * ASZ + 2048 + sLds]);
    };

    stage(0, 0);
    stage(1, 1);

    int bf = 0;
    for (int t = 0; t < NT; ++t) {
        if (t < NT - 1) asm volatile("s_waitcnt vmcnt(4)" ::: "memory");
        else            asm volatile("s_waitcnt vmcnt(0)" ::: "memory");
        barrier_fence();
        const int bf2 = (bf + 2 >= 3) ? bf - 1 : bf + 2;
        if (t + 2 < NT) stage(t + 2, bf2);

        const int ab = bf * ASZ + (wm * 64 + fl) * 32 + cSlot;
        const int bb = bf * ASZ + (wn * 64 + fl) * 32 + cSlot;
        bf16x8 a[4], b[4];
        #pragma unroll
        for (int mt = 0; mt < 4; ++mt)
            a[mt] = *(const bf16x8*)&As[ab + mt * 512];
        #pragma unroll
        for (int nt = 0; nt < 4; ++nt)
            b[nt] = *(const bf16x8*)&Bs[bb + nt * 512];

        #pragma unroll
        for (int mt = 0; mt < 4; ++mt)
            #pragma unroll
            for (int nt = 0; nt < 4; ++nt)
                acc[mt][nt] = __builtin_amdgcn_mfma_f32_16x16x32_bf16(
                    a[mt], b[nt], acc[mt][nt], 0, 0, 0);

        bf = (bf + 1 >= 3) ? 0 : bf + 1;
    }

    #pragma unroll
    for (int mt = 0; mt < 4; ++mt)
        #pragma unroll
        for (int nt = 0; nt < 4; ++nt) {
            const int colb = n0 + wn * 64 + nt * 16 + fl;
            #pragma unroll
            for (int r = 0; r < 4; ++r) {
                const int row = m0 + wm * 64 + mt * 16 + q4 * 4 + r;
                Cf[(size_t)row * N + colb] = acc[mt][nt][r];
            }
        }
}

// ---------- causal flash attention (round-4/6 LDS-staged version) ----------
// Work-paired causal scheme: block handles q-tiles lo=bx and hi=31-bx
// (exactly 33 tile-works per block -> perfect balance, 512 blocks = 2/CU).
// Dual iterations (j<=lo) share every K/V LDS read across 2x MFMA work.
// transposed-S, no-max softmax, deferred l; async dbuf K/V staging w/ XOR swizzle.
__global__ __launch_bounds__(256, 2)
void attn_kernel(const u16* __restrict__ qkv,
                 const u16* __restrict__ vsrc,
                 u16* __restrict__ y)
{
    constexpr int T = 2048;
    const int lo  = blockIdx.x;          // 0..15
    const int hi  = 31 - lo;             // 16..31
    const int bh  = blockIdx.y;
    const int b   = bh >> 4;
    const int h   = bh & 15;
    const int kvh = h >> 2;

    const int tid  = threadIdx.x;
    const int w    = tid >> 6;
    const int lane = tid & 63;
    const int fl   = lane & 15;
    const int q4   = lane >> 4;

    __shared__ __align__(16) u16 Ks[2][64 * 128];   // [kv][d], chunk-swizzled
    __shared__ __align__(16) u16 Vt[2][128 * 64];   // [d][kv], chunk-swizzled
    __shared__ __align__(16) u16 Ps[64 * 72];       // [q][kv], per-wave rows

    const u16* Qg = qkv  + (size_t)(b * T) * 3072 + (h << 7);
    const u16* Kg = qkv  + (size_t)(b * T) * 3072 + 2048 + (kvh << 7);
    const u16* Vg = vsrc + (size_t)((b * 4 + kvh) * 128) * T;

    // Q fragments for both tiles (pre-scaled by 1/sqrt(D) in gemm_qkv)
    bf16x8 qf0[4], qf1[4];
    #pragma unroll
    for (int kc = 0; kc < 4; ++kc) {
        qf0[kc] = *(const bf16x8*)&Qg[(size_t)(lo * 64 + w * 16 + fl) * 3072 + kc * 32 + q4 * 8];
        qf1[kc] = *(const bf16x8*)&Qg[(size_t)(hi * 64 + w * 16 + fl) * 3072 + kc * 32 + q4 * 8];
    }

    // staging: per-lane swizzled global offsets, wave-uniform LDS chunk bases
    int goffK[4], goffV[4], ldsC[4];
    #pragma unroll
    for (int i = 0; i < 4; ++i) {
        const int c  = w + 4 * i;                 // 1KB chunk 0..15
        const int rk = 4 * c + (lane >> 4);       // K row in tile
        const int lk = (lane & 15) ^ (rk & 15);
        goffK[i] = rk * 3072 + lk * 8;
        const int rv = 8 * c + (lane >> 3);       // V row (d index)
        const int lv = (lane & 7) ^ ((lane >> 3) & 7);
        goffV[i] = rv * T + lv * 8;
        ldsC[i]  = c * 512;
    }

    #pragma unroll
    for (int i = 0; i < 4; ++i) {                 // prefetch tile 0 -> buf 0
        async16(Kg + goffK[i], &Ks[0][ldsC[i]]);
        async16(Vg + goffV[i], &Vt[0][ldsC[i]]);
    }

    float l0 = 0.f, l1 = 0.f;                     // per-lane partial sums
    f32x4 o0[8], o1[8];
    #pragma unroll
    for (int dt = 0; dt < 8; ++dt) {
        o0[dt] = f32x4{0.f, 0.f, 0.f, 0.f};
        o1[dt] = f32x4{0.f, 0.f, 0.f, 0.f};
    }

    const int psrow = (w * 16 + fl) * 72;

    for (int j = 0; j <= hi; ++j) {
        __syncthreads();   // drains vmcnt: buf[j&1] ready; buf[j^1] released

        if (j < hi) {      // prefetch j+1, in flight during compute
            const u16* kb = Kg + (size_t)(j + 1) * 64 * 3072;
            const u16* vb = Vg + (j + 1) * 64;
            const int nb = (j + 1) & 1;
            #pragma unroll
            for (int i = 0; i < 4; ++i) {
                async16(kb + goffK[i], &Ks[nb][ldsC[i]]);
                async16(vb + goffV[i], &Vt[nb][ldsC[i]]);
            }
        }
        const int cb = j & 1;
        const bool dual = (j <= lo);

        // S^T = K * Q^T for ctx1 (always) and ctx0 (dual), sharing aK reads
        f32x4 s0[4], s1[4];
        #pragma unroll
        for (int nt = 0; nt < 4; ++nt) {
            s0[nt] = f32x4{0.f, 0.f, 0.f, 0.f};
            s1[nt] = f32x4{0.f, 0.f, 0.f, 0.f};
        }
        if (dual) {
            #pragma unroll
            for (int kc = 0; kc < 4; ++kc)
                #pragma unroll
                for (int nt = 0; nt < 4; ++nt) {
                    bf16x8 aK = *(const bf16x8*)
                        &Ks[cb][(nt * 16 + fl) * 128 + (((kc << 2) + q4) ^ fl) * 8];
                    s1[nt] = __builtin_amdgcn_mfma_f32_16x16x32_bf16(aK, qf1[kc], s1[nt], 0, 0, 0);
                    s0[nt] = __builtin_amdgcn_mfma_f32_16x16x32_bf16(aK, qf0[kc], s0[nt], 0, 0, 0);
                }
        } else {
            #pragma unroll
            for (int kc = 0; kc < 4; ++kc)
                #pragma unroll
                for (int nt = 0; nt < 4; ++nt) {
                    bf16x8 aK = *(const bf16x8*)
                        &Ks[cb][(nt * 16 + fl) * 128 + (((kc << 2) + q4) ^ fl) * 8];
                    s1[nt] = __builtin_amdgcn_mfma_f32_16x16x32_bf16(aK, qf1[kc], s1[nt], 0, 0, 0);
                }
        }

        // causal masks (diagonal tiles only; j==lo is always dual, j==hi never)
        if (j == lo || j == hi) {
            const int qloc = w * 16 + fl;
            #pragma unroll
            for (int nt = 0; nt < 4; ++nt)
                #pragma unroll
                for (int r = 0; r < 4; ++r)
                    if (nt * 16 + q4 * 4 + r > qloc) {
                        if (j == lo) s0[nt][r] = -3e38f;
                        else         s1[nt][r] = -3e38f;
                    }
        }

        // ctx0 (dual only): exp + P write + PV
        if (dual) {
            #pragma unroll
            for (int nt = 0; nt < 4; ++nt) {
                ushort4 pw;
                float p0 = __expf(s0[nt][0]);
                float p1 = __expf(s0[nt][1]);
                float p2 = __expf(s0[nt][2]);
                float p3 = __expf(s0[nt][3]);
                l0 += (p0 + p1) + (p2 + p3);
                pw.x = f2bf(p0); pw.y = f2bf(p1); pw.z = f2bf(p2); pw.w = f2bf(p3);
                *(ushort4*)&Ps[psrow + nt * 16 + q4 * 4] = pw;
            }
            asm volatile("s_waitcnt lgkmcnt(0)" ::: "memory");
            #pragma unroll
            for (int kc = 0; kc < 2; ++kc) {
                bf16x8 ap = *(const bf16x8*)&Ps[psrow + kc * 32 + q4 * 8];
                #pragma unroll
                for (int dt = 0; dt < 8; ++dt) {
                    bf16x8 bv = *(const bf16x8*)
                        &Vt[cb][(dt * 16 + fl) * 64 + (((kc << 2) + q4) ^ (fl & 7)) * 8];
                    o0[dt] = __builtin_amdgcn_mfma_f32_16x16x32_bf16(ap, bv, o0[dt], 0, 0, 0);
                }
            }
        }

        // ctx1: exp + P write (same per-wave Ps rows; DS pipe is in-order
        // per wave, so prior ap reads complete before these writes land) + PV
        #pragma unroll
        for (int nt = 0; nt < 4; ++nt) {
            ushort4 pw;
            float p0 = __expf(s1[nt][0]);
            float p1 = __expf(s1[nt][1]);
            float p2 = __expf(s1[nt][2]);
            float p3 = __expf(s1[nt][3]);
            l1 += (p0 + p1) + (p2 + p3);
            pw.x = f2bf(p0); pw.y = f2bf(p1); pw.z = f2bf(p2); pw.w = f2bf(p3);
            *(ushort4*)&Ps[psrow + nt * 16 + q4 * 4] = pw;
        }
        asm volatile("s_waitcnt lgkmcnt(0)" ::: "memory");
        #pragma unroll
        for (int kc = 0; kc < 2; ++kc) {
            bf16x8 ap = *(const bf16x8*)&Ps[psrow + kc * 32 + q4 * 8];
            #pragma unroll
            for (int dt = 0; dt < 8; ++dt) {
                bf16x8 bv = *(const bf16x8*)
                    &Vt[cb][(dt * 16 + fl) * 64 + (((kc << 2) + q4) ^ (fl & 7)) * 8];
                o1[dt] = __builtin_amdgcn_mfma_f32_16x16x32_bf16(ap, bv, o1[dt], 0, 0, 0);
            }
        }
    }

    // deferred l reductions + epilogue for both contexts
    l0 += __shfl_xor(l0, 16, 64);
    l0 += __shfl_xor(l0, 32, 64);
    l1 += __shfl_xor(l1, 16, 64);
    l1 += __shfl_xor(l1, 32, 64);
    const float li0 = 1.0f / l0;
    const float li1 = 1.0f / l1;

    float lr0[4], lr1[4];
    #pragma unroll
    for (int r = 0; r < 4; ++r) {
        lr0[r] = __shfl(li0, q4 * 4 + r, 16);
        lr1[r] = __shfl(li1, q4 * 4 + r, 16);
    }
    #pragma unroll
    for (int dt = 0; dt < 8; ++dt)
        #pragma unroll
        for (int r = 0; r < 4; ++r) {
            const int row0 = lo * 64 + w * 16 + q4 * 4 + r;
            const int row1 = hi * 64 + w * 16 + q4 * 4 + r;
            y[(size_t)(b * T + row0) * 2048 + (h << 7) + dt * 16 + fl] =
                f2bf(o0[dt][r] * lr0[r]);
            y[(size_t)(b * T + row1) * 2048 + (h << 7) + dt * 16 + fl] =
                f2bf(o1[dt][r] * lr1[r]);
        }
}

// ---------- launch ----------------------------------------------------------
extern "C" void kernel_launch(void* const* d_in, const int* in_sizes, int n_in,
                              void* d_out, int out_size, void* d_ws, size_t ws_size,
                              hipStream_t stream)
{
    const float* x   = (const float*)d_in[0];
    const float* Wq  = (const float*)d_in[1];
    const float* Wkv = (const float*)d_in[2];
    const float* Wo  = (const float*)d_in[3];
    float* out = (float*)d_out;

    u16* wob  = (u16*)d_ws;                          // [2048 x 2048]
    u16* qkv  = wob + (size_t)2048 * 2048;           // [4096, 3072]
    u16* vbuf = qkv + (size_t)4096 * 3072;           // V^T [B*KV*128, 2048]
    u16* y    = vbuf + (size_t)2 * 4 * 128 * 2048;   // [4096, 2048]

    // 768 gemm tiles + 64 wo-convert blocks, one dispatch
    gemm_qkv_f32<<<832, 512, 0, stream>>>(x, Wq, Wkv, Wo, wob, qkv, vbuf, 4096, 2048);

    attn_kernel<<<dim3(16, 32), 256, 0, stream>>>(qkv, vbuf, y);

    dim3 g2(2048 / 128, 4096 / 128);                 // 16 x 32 = 512 wgs (%8==0)
    gemm128r<<<g2, 256, 0, stream>>>(y, wob, out, 4096, 2048, 2048);
}